// Round 5
// baseline (165.482 us; speedup 1.0000x reference)
//
#include <hip/hip_runtime.h>
#include <math.h>

#define KBINS 8192
#define DDIM  16384      // 2*K
#define HID   2048
#define LASTROW 16384    // the t row of W1 (row index D)

#define C1 16            // rows per mv1 block
#define NB1 1024         // 16384/16 (t-row handled in h_reduce)
#define C2 16            // rows per mv2 block
#define NB2 128          // 2048/16

static constexpr float SQRT2_F  = 1.4142135623730951f;
static constexpr float INVSQ2PI = 0.3989422804014327f;   // 1/sqrt(2*pi)

// Branch-free erf approximation (Abramowitz-Stegun 7.1.26), |err| < 1.5e-7.
// Only used for the single clamped column j==4096 (one eval per row).
__device__ __forceinline__ float fast_erff(float x) {
    float ax = fabsf(x);
    float t  = 1.0f / fmaf(0.3275911f, ax, 1.0f);
    float p  = t * (0.254829592f +
               t * (-0.284496736f +
               t * (1.421413741f +
               t * (-1.453152027f +
               t * 1.061405429f))));
    float r = 1.0f - p * __expf(-ax * ax);
    return copysignf(r, x);
}

// ---- K1: partial matvec1 over mu rows only. grid (2, 1024), block 256. ----
// 2048 blocks = 8 blocks/CU = 32 waves/CU: full occupancy to saturate HBM reads.
__global__ void __launch_bounds__(256, 8)
mv1_partial(const float* __restrict__ mu, const float* __restrict__ W1,
            float* __restrict__ part1) {
    __shared__ float a_s[C1];
    int r0 = blockIdx.y * C1;
    if (threadIdx.x < C1) a_s[threadIdx.x] = mu[r0 + threadIdx.x];
    __syncthreads();
    int c0 = (blockIdx.x * 256 + threadIdx.x) * 4;   // 0..2044
    float4 acc0 = {0.f, 0.f, 0.f, 0.f};
    float4 acc1 = {0.f, 0.f, 0.f, 0.f};
    const float* wp = W1 + (size_t)r0 * HID + c0;
#pragma unroll
    for (int k = 0; k < C1; k += 2) {
        float a0 = a_s[k];
        float a1 = a_s[k + 1];
        const float4 w0 = *reinterpret_cast<const float4*>(wp + (size_t)k * HID);
        const float4 w1 = *reinterpret_cast<const float4*>(wp + (size_t)(k + 1) * HID);
        acc0.x += a0 * w0.x; acc0.y += a0 * w0.y; acc0.z += a0 * w0.z; acc0.w += a0 * w0.w;
        acc1.x += a1 * w1.x; acc1.y += a1 * w1.y; acc1.z += a1 * w1.z; acc1.w += a1 * w1.w;
    }
    float4 acc = {acc0.x + acc1.x, acc0.y + acc1.y, acc0.z + acc1.z, acc0.w + acc1.w};
    *reinterpret_cast<float4*>(part1 + (size_t)blockIdx.y * HID + c0) = acc;
}

// ---- K2: h = leaky(b1 + sum_rb part1 + t * W1[lastrow]). grid 32, block 256. ----
__global__ void __launch_bounds__(256)
h_reduce(const float* __restrict__ part1, const float* __restrict__ b1,
         const float* __restrict__ W1, const float* __restrict__ t,
         float* __restrict__ h) {
    __shared__ float red[4][64];
    int lane = threadIdx.x & 63;
    int sub  = threadIdx.x >> 6;          // 0..3
    int col  = blockIdx.x * 64 + lane;
    float s = 0.f;
#pragma unroll 8
    for (int rb = sub; rb < NB1; rb += 4)
        s += part1[(size_t)rb * HID + col];
    red[sub][lane] = s;
    __syncthreads();
    if (threadIdx.x < 64) {
        int c = blockIdx.x * 64 + threadIdx.x;
        float v = b1[c] + t[0] * W1[(size_t)LASTROW * HID + c];
        v += red[0][threadIdx.x] + red[1][threadIdx.x]
           + red[2][threadIdx.x] + red[3][threadIdx.x];
        h[c] = (v >= 0.f) ? v : 0.01f * v;
    }
}

// ---- K3: partial matvec2. grid (16, 128), block 256. ----
__global__ void __launch_bounds__(256, 8)
mv2_partial(const float* __restrict__ h, const float* __restrict__ W2,
            float* __restrict__ part2) {
    __shared__ float hs[C2];
    int r0 = blockIdx.y * C2;
    if (threadIdx.x < C2) hs[threadIdx.x] = h[r0 + threadIdx.x];
    __syncthreads();
    int c0 = (blockIdx.x * 256 + threadIdx.x) * 4;   // 0..16380
    float4 acc0 = {0.f, 0.f, 0.f, 0.f};
    float4 acc1 = {0.f, 0.f, 0.f, 0.f};
    const float* wp = W2 + (size_t)r0 * DDIM + c0;
#pragma unroll
    for (int k = 0; k < C2; k += 2) {
        float a0 = hs[k];
        float a1 = hs[k + 1];
        const float4 w0 = *reinterpret_cast<const float4*>(wp + (size_t)k * DDIM);
        const float4 w1 = *reinterpret_cast<const float4*>(wp + (size_t)(k + 1) * DDIM);
        acc0.x += a0 * w0.x; acc0.y += a0 * w0.y; acc0.z += a0 * w0.z; acc0.w += a0 * w0.w;
        acc1.x += a1 * w1.x; acc1.y += a1 * w1.y; acc1.z += a1 * w1.z; acc1.w += a1 * w1.w;
    }
    float4 acc = {acc0.x + acc1.x, acc0.y + acc1.y, acc0.z + acc1.z, acc0.w + acc1.w};
    *reinterpret_cast<float4*>(part2 + (size_t)blockIdx.y * DDIM + c0) = acc;
}

// ---- K4: mu_x / sigma_x scalars. grid 32, block 256 (8192 rows). ----
__global__ void __launch_bounds__(256)
scalars(const float* __restrict__ part2, const float* __restrict__ b2,
        const float* __restrict__ mu, const float* __restrict__ t,
        const float* __restrict__ gamma,
        float* __restrict__ mu_x, float* __restrict__ sigma_x) {
    int i = blockIdx.x * 256 + threadIdx.x;
    float s0 = b2[i];
    float s1 = b2[i + KBINS];
#pragma unroll 8
    for (int rb = 0; rb < NB2; ++rb) {
        s0 += part2[(size_t)rb * DDIM + i];
        s1 += part2[(size_t)rb * DDIM + i + KBINS];
    }
    float g  = gamma[0];
    float pe = 1.0f / (1.0f - g);
    float pm = g - pe;
    bool use_nn = (t[0] >= 1e-10f);
    float mx = powf(mu[i], pm) * powf(s0, pe);
    float sx = powf(1.0f - g, -0.5f) * expf(0.5f * s1);
    mu_x[i]    = use_nn ? mx : 0.0f;
    sigma_x[i] = use_nn ? sx : 1.0f;
}

// ---- K5: out[i][j] = F_i(kr[j]) - F_i(kl[j]) via midpoint rule. ----
// grid 2048 blocks, each handles 4 rows (grid-stride): i = bid + r*2048.
// j <= 4095: F(kr)-F(kl) = Delta*pdf(mid), err ~1e-13 (sigma_x ~ 1.4).
// j == 4096: kr clamps to 1 -> 0.5*(1-erf(z)). j >= 4097: exactly 0.
__global__ void __launch_bounds__(256, 8)
cdf_row(const float* __restrict__ mu_x, const float* __restrict__ sigma_x,
        float* __restrict__ out) {
    int tid = threadIdx.x;
#pragma unroll
    for (int rr = 0; rr < 4; ++rr) {
        int i = blockIdx.x + rr * 2048;
        float m    = mu_x[i];
        float invs = 1.0f / sigma_x[i];
        const float sc = 2.0f / 8191.0f;
        float A    = sc * invs;                          // du/dj
        float B    = (-1.0f / 8191.0f - m) * invs;       // u at j=0
        float coef = INVSQ2PI * A;                       // Delta * pdf scale
        float* orow = out + (size_t)i * KBINS;
#pragma unroll
        for (int it = 0; it < 8; ++it) {
            int j0 = it * 1024 + tid * 4;
            float4 r;
            if (j0 < 4096) {
                float u0 = fmaf((float)j0, A, B);
                float u1 = u0 + A;
                float u2 = u1 + A;
                float u3 = u2 + A;
                r.x = coef * __expf(-0.5f * u0 * u0);
                r.y = coef * __expf(-0.5f * u1 * u1);
                r.z = coef * __expf(-0.5f * u2 * u2);
                r.w = coef * __expf(-0.5f * u3 * u3);
            } else if (j0 == 4096) {
                float z = (8190.0f / 8191.0f - m) * invs * (1.0f / SQRT2_F);
                r.x = 0.5f * (1.0f - fast_erff(z));
                r.y = r.z = r.w = 0.f;
            } else {
                r.x = r.y = r.z = r.w = 0.f;
            }
            *reinterpret_cast<float4*>(orow + j0) = r;
        }
    }
}

extern "C" void kernel_launch(void* const* d_in, const int* in_sizes, int n_in,
                              void* d_out, int out_size, void* d_ws, size_t ws_size,
                              hipStream_t stream) {
    const float* mu    = (const float*)d_in[0];
    const float* t     = (const float*)d_in[1];
    const float* gamma = (const float*)d_in[2];
    const float* W1    = (const float*)d_in[3];
    const float* b1    = (const float*)d_in[4];
    const float* W2    = (const float*)d_in[5];
    const float* b2    = (const float*)d_in[6];
    float* out = (float*)d_out;

    float* ws      = (float*)d_ws;
    float* part1   = ws;                             // 1024*2048 = 2,097,152 floats (8 MB)
    float* h       = part1 + (size_t)NB1 * HID;      // 2048
    float* part2   = h + HID;                        // 128*16384 = 2,097,152 floats (8 MB)
    float* mu_x    = part2 + (size_t)NB2 * DDIM;     // 8192
    float* sigma_x = mu_x + KBINS;                   // 8192

    mv1_partial<<<dim3(2, NB1),  dim3(256), 0, stream>>>(mu, W1, part1);
    h_reduce   <<<dim3(32),      dim3(256), 0, stream>>>(part1, b1, W1, t, h);
    mv2_partial<<<dim3(16, NB2), dim3(256), 0, stream>>>(h, W2, part2);
    scalars    <<<dim3(32),      dim3(256), 0, stream>>>(part2, b2, mu, t, gamma, mu_x, sigma_x);
    cdf_row    <<<dim3(2048),    dim3(256), 0, stream>>>(mu_x, sigma_x, out);
}

// Round 6
// 144.217 us; speedup vs baseline: 1.1475x; 1.1475x over previous
//
#include <hip/hip_runtime.h>
#include <math.h>

#define KBINS 8192
#define DDIM  16384      // 2*K
#define HID   2048
#define LASTROW 16384    // the t row of W1 (row index D)

#define C1 16            // rows per mv1 block
#define NB1 1024         // 16384/16 chunks  (t-row handled in mv2h)
#define C2 8             // rows per mv2 block
#define NB2 256          // 2048/8 chunks

static constexpr float SQRT2_F  = 1.4142135623730951f;
static constexpr float INVSQ2PI = 0.3989422804014327f;   // 1/sqrt(2*pi)

// Branch-free erf approximation (A&S 7.1.26), |err| < 1.5e-7.
// Only used for the single clamped column j==4096 (one eval per row).
__device__ __forceinline__ float fast_erff(float x) {
    float ax = fabsf(x);
    float t  = 1.0f / fmaf(0.3275911f, ax, 1.0f);
    float p  = t * (0.254829592f +
               t * (-0.284496736f +
               t * (1.421413741f +
               t * (-1.453152027f +
               t * 1.061405429f))));
    float r = 1.0f - p * __expf(-ax * ax);
    return copysignf(r, x);
}

// ---- K1: partial matvec1. grid 1024, block 256. Block reads a CONTIGUOUS
// 128 KB slab: 16 rows x 8 KB (full 2048-col rows, two float4 per thread).
__global__ void __launch_bounds__(256)
mv1_partial(const float* __restrict__ mu, const float* __restrict__ W1,
            float* __restrict__ part1) {
    __shared__ float a_s[C1];
    int r0 = blockIdx.x * C1;
    if (threadIdx.x < C1) a_s[threadIdx.x] = mu[r0 + threadIdx.x];
    __syncthreads();
    int c0 = threadIdx.x * 4;                 // 0..1020
    float4 acc0 = {0.f, 0.f, 0.f, 0.f};       // cols c0
    float4 acc1 = {0.f, 0.f, 0.f, 0.f};       // cols c0+1024
    const float* wp = W1 + (size_t)r0 * HID;
#pragma unroll
    for (int k = 0; k < C1; ++k) {
        float a = a_s[k];
        const float4 w0 = *reinterpret_cast<const float4*>(wp + (size_t)k * HID + c0);
        const float4 w1 = *reinterpret_cast<const float4*>(wp + (size_t)k * HID + c0 + 1024);
        acc0.x += a * w0.x; acc0.y += a * w0.y; acc0.z += a * w0.z; acc0.w += a * w0.w;
        acc1.x += a * w1.x; acc1.y += a * w1.y; acc1.z += a * w1.z; acc1.w += a * w1.w;
    }
    float* pp = part1 + (size_t)blockIdx.x * HID;
    *reinterpret_cast<float4*>(pp + c0)        = acc0;
    *reinterpret_cast<float4*>(pp + c0 + 1024) = acc1;
}

// ---- K2': fused h-recompute + partial matvec2. grid (2, 256), block 256. ----
// Stage 1: block rebuilds its 8 h values from part1 (fixed order -> deterministic,
// identical across bx). Stage 2: streams 8 rows x 32 KB contiguous half-rows of W2.
__global__ void __launch_bounds__(256)
mv2h(const float* __restrict__ part1, const float* __restrict__ b1,
     const float* __restrict__ W1, const float* __restrict__ t,
     const float* __restrict__ W2, float* __restrict__ part2) {
    __shared__ float red[32][8];
    __shared__ float hs[C2];
    int r0    = blockIdx.y * C2;              // h rows 8*by .. +8
    int cbase = blockIdx.x * 8192;            // col half
    int col_l = threadIdx.x & 7;              // 0..7
    int sub   = threadIdx.x >> 3;             // 0..31
    {
        float s = 0.f;
        const float* p = part1 + r0 + col_l;
#pragma unroll 8
        for (int m = 0; m < 32; ++m)
            s += p[(size_t)(sub + (m << 5)) * HID];
        red[sub][col_l] = s;
    }
    __syncthreads();
    if (threadIdx.x < C2) {
        int r = r0 + threadIdx.x;
        float v = b1[r] + t[0] * W1[(size_t)LASTROW * HID + r];
#pragma unroll
        for (int p = 0; p < 32; ++p) v += red[p][threadIdx.x];
        hs[threadIdx.x] = (v >= 0.f) ? v : 0.01f * v;   // leaky relu
    }
    __syncthreads();
    int c0 = threadIdx.x * 4;                 // 0..1020
    float4 acc[8];
#pragma unroll
    for (int q = 0; q < 8; ++q) acc[q] = {0.f, 0.f, 0.f, 0.f};
    const float* wp = W2 + (size_t)r0 * DDIM + cbase + c0;
#pragma unroll 2
    for (int k = 0; k < C2; ++k) {
        float a = hs[k];
        const float* wr = wp + (size_t)k * DDIM;
#pragma unroll
        for (int q = 0; q < 8; ++q) {
            const float4 w = *reinterpret_cast<const float4*>(wr + q * 1024);
            acc[q].x += a * w.x; acc[q].y += a * w.y;
            acc[q].z += a * w.z; acc[q].w += a * w.w;
        }
    }
    float* pp = part2 + (size_t)blockIdx.y * DDIM + cbase + c0;
#pragma unroll
    for (int q = 0; q < 8; ++q)
        *reinterpret_cast<float4*>(pp + q * 1024) = acc[q];
}

// ---- K3': mu_x / sigma_x. grid 256, block 256. Block owns 32 cols; 8-way
// chunk-split + LDS reduce -> coalesced 128B segments, high parallelism. ----
__global__ void __launch_bounds__(256)
scalars(const float* __restrict__ part2, const float* __restrict__ b2,
        const float* __restrict__ mu, const float* __restrict__ t,
        const float* __restrict__ gamma,
        float* __restrict__ mu_x, float* __restrict__ sigma_x) {
    __shared__ float red0[8][32];
    __shared__ float red1[8][32];
    int col_l = threadIdx.x & 31;             // 0..31
    int sub   = threadIdx.x >> 5;             // 0..7
    int c     = blockIdx.x * 32 + col_l;      // 0..8191
    float s0 = 0.f, s1 = 0.f;
    const float* p0 = part2 + c;
    const float* p1 = part2 + c + KBINS;
#pragma unroll 8
    for (int m = 0; m < 32; ++m) {
        size_t off = (size_t)(sub + (m << 3)) * DDIM;
        s0 += p0[off];
        s1 += p1[off];
    }
    red0[sub][col_l] = s0;
    red1[sub][col_l] = s1;
    __syncthreads();
    if (threadIdx.x < 32) {
        int cc = blockIdx.x * 32 + threadIdx.x;
        float v0 = b2[cc];
        float v1 = b2[cc + KBINS];
#pragma unroll
        for (int p = 0; p < 8; ++p) { v0 += red0[p][threadIdx.x]; v1 += red1[p][threadIdx.x]; }
        float g  = gamma[0];
        float pe = 1.0f / (1.0f - g);
        float pm = g - pe;
        bool use_nn = (t[0] >= 1e-10f);
        float mx = powf(mu[cc], pm) * powf(v0, pe);
        float sx = powf(1.0f - g, -0.5f) * expf(0.5f * v1);
        mu_x[cc]    = use_nn ? mx : 0.0f;
        sigma_x[cc] = use_nn ? sx : 1.0f;
    }
}

// ---- K4': out[i][j] = F_i(kr[j]) - F_i(kl[j]) via midpoint rule. ----
// grid 4096 blocks x 2 consecutive rows each (64 KB contiguous per block).
// j <= 4095: Delta*pdf(mid), err ~1e-13. j == 4096: 0.5*(1-erf(z)). j > 4096: 0.
__global__ void __launch_bounds__(256)
cdf_row(const float* __restrict__ mu_x, const float* __restrict__ sigma_x,
        float* __restrict__ out) {
    int tid = threadIdx.x;
    for (int rr = 0; rr < 2; ++rr) {
        int i = blockIdx.x * 2 + rr;
        float m    = mu_x[i];
        float invs = 1.0f / sigma_x[i];
        const float sc = 2.0f / 8191.0f;
        float A    = sc * invs;                          // du/dj
        float B    = (-1.0f / 8191.0f - m) * invs;       // u at j=0
        float coef = INVSQ2PI * A;                       // Delta * pdf scale
        float* orow = out + (size_t)i * KBINS;
#pragma unroll
        for (int it = 0; it < 8; ++it) {
            int j0 = it * 1024 + tid * 4;
            float4 r;
            if (j0 < 4096) {
                float u0 = fmaf((float)j0, A, B);
                float u1 = u0 + A;
                float u2 = u1 + A;
                float u3 = u2 + A;
                r.x = coef * __expf(-0.5f * u0 * u0);
                r.y = coef * __expf(-0.5f * u1 * u1);
                r.z = coef * __expf(-0.5f * u2 * u2);
                r.w = coef * __expf(-0.5f * u3 * u3);
            } else if (j0 == 4096) {
                float z = (8190.0f / 8191.0f - m) * invs * (1.0f / SQRT2_F);
                r.x = 0.5f * (1.0f - fast_erff(z));
                r.y = r.z = r.w = 0.f;
            } else {
                r.x = r.y = r.z = r.w = 0.f;
            }
            *reinterpret_cast<float4*>(orow + j0) = r;
        }
    }
}

extern "C" void kernel_launch(void* const* d_in, const int* in_sizes, int n_in,
                              void* d_out, int out_size, void* d_ws, size_t ws_size,
                              hipStream_t stream) {
    const float* mu    = (const float*)d_in[0];
    const float* t     = (const float*)d_in[1];
    const float* gamma = (const float*)d_in[2];
    const float* W1    = (const float*)d_in[3];
    const float* b1    = (const float*)d_in[4];
    const float* W2    = (const float*)d_in[5];
    const float* b2    = (const float*)d_in[6];
    float* out = (float*)d_out;

    float* ws      = (float*)d_ws;
    float* part1   = ws;                             // 1024*2048 = 8 MB
    float* part2   = part1 + (size_t)NB1 * HID;      // 256*16384 = 16 MB
    float* mu_x    = part2 + (size_t)NB2 * DDIM;     // 8192
    float* sigma_x = mu_x + KBINS;                   // 8192

    mv1_partial<<<dim3(NB1),     dim3(256), 0, stream>>>(mu, W1, part1);
    mv2h       <<<dim3(2, NB2),  dim3(256), 0, stream>>>(part1, b1, W1, t, W2, part2);
    scalars    <<<dim3(256),     dim3(256), 0, stream>>>(part2, b2, mu, t, gamma, mu_x, sigma_x);
    cdf_row    <<<dim3(4096),    dim3(256), 0, stream>>>(mu_x, sigma_x, out);
}